// Round 6
// baseline (104.757 us; speedup 1.0000x reference)
//
#include <hip/hip_runtime.h>
#include <hip/hip_bf16.h>

#define NNODES 100000
#define NEDGES 1600000
#define IN_C   256
#define OUT_C  128

typedef short bf16x8 __attribute__((ext_vector_type(8)));
typedef float f32x4  __attribute__((ext_vector_type(4)));

static __device__ __forceinline__ unsigned short f2bf(float f) {
    union { float f; unsigned u; } c; c.f = f;
    unsigned r = c.u + 0x7fffu + ((c.u >> 16) & 1u);   // round-to-nearest-even
    return (unsigned short)(r >> 16);
}
static __device__ __forceinline__ float bflo(unsigned u) {
    union { unsigned u; float f; } c; c.u = u << 16; return c.f;
}
static __device__ __forceinline__ float bfhi(unsigned u) {
    union { unsigned u; float f; } c; c.u = u & 0xffff0000u; return c.f;
}

union BF8 { bf16x8 v; unsigned short s[8]; };

// ---------------------------------------------------------------------------
// GEMM: H(bf16) = X @ W^T.  (unchanged from round 4)
// W staged once into 64KB XOR-swizzled LDS; X loaded directly into MFMA
// A-fragments from global; barrier-free K-loop; 8 acc chains x 8 k-slices.
// ---------------------------------------------------------------------------
__global__ __launch_bounds__(512, 4) void gemm_xwt(const float* __restrict__ X,
                                                   const float* __restrict__ W,
                                                   unsigned short* __restrict__ H) {
    __shared__ unsigned short Wsh[128 * 256];   // bf16 bits, [n][k], swizzled, 64KB

    const int tid  = threadIdx.x;
    const int lane = tid & 63;
    const int wid  = tid >> 6;                  // 0..7

#pragma unroll
    for (int p = 0; p < 16; ++p) {
        int idx = p * 512 + tid;                // 0..8191 float4 index
        int n   = idx >> 6;                     // 0..127
        int c4  = idx & 63;                     // float4 column
        float4 v = *(const float4*)(W + (size_t)n * IN_C + c4 * 4);
        int byte = (n * 512 + c4 * 8) ^ ((n & 7) << 4);
        *(ushort4*)((char*)Wsh + byte) =
            make_ushort4(f2bf(v.x), f2bf(v.y), f2bf(v.z), f2bf(v.w));
    }
    __syncthreads();

    const int r0   = blockIdx.x * 128 + wid * 16;
    int arow = r0 + (lane & 15);
    if (arow > NNODES - 1) arow = NNODES - 1;   // clamp (tail rows discarded)
    const float* xrow = X + (size_t)arow * IN_C + (lane >> 4) * 8;

    f32x4 acc[8] = {};
#pragma unroll
    for (int ks = 0; ks < 8; ++ks) {
        float4 a0 = *(const float4*)(xrow + ks * 32);
        float4 a1 = *(const float4*)(xrow + ks * 32 + 4);
        BF8 t;
        t.s[0] = f2bf(a0.x); t.s[1] = f2bf(a0.y); t.s[2] = f2bf(a0.z); t.s[3] = f2bf(a0.w);
        t.s[4] = f2bf(a1.x); t.s[5] = f2bf(a1.y); t.s[6] = f2bf(a1.z); t.s[7] = f2bf(a1.w);
        const int kb = ks * 64 + (lane >> 4) * 16;      // byte offset in W row
#pragma unroll
        for (int n8 = 0; n8 < 8; ++n8) {
            int nr   = n8 * 16 + (lane & 15);
            int byte = (nr * 512 + kb) ^ ((nr & 7) << 4);
            bf16x8 b = *(const bf16x8*)((const char*)Wsh + byte);
            acc[n8] = __builtin_amdgcn_mfma_f32_16x16x32_bf16(t.v, b, acc[n8],
                                                              0, 0, 0);
        }
    }

#pragma unroll
    for (int n8 = 0; n8 < 8; ++n8) {
#pragma unroll
        for (int r = 0; r < 4; ++r) {
            int grow = r0 + (lane >> 4) * 4 + r;
            if (grow < NNODES)
                H[(size_t)grow * OUT_C + n8 * 16 + (lane & 15)] = f2bf(acc[n8][r]);
        }
    }
}

// ---------------------------------------------------------------------------
// rowptr[r] = lower_bound(A_rows, r)  (A_rows sorted).  r in [0, N].
// ---------------------------------------------------------------------------
__global__ __launch_bounds__(256) void build_rowptr(const int* __restrict__ rows,
                                                    int* __restrict__ rowptr) {
    int r = blockIdx.x * 256 + threadIdx.x;
    if (r > NNODES) return;
    int lo = 0, hi = NEDGES;
    while (lo < hi) {
        int mid = (lo + hi) >> 1;
        if (rows[mid] < r) lo = mid + 1; else hi = mid;
    }
    rowptr[r] = lo;
}

// ---------------------------------------------------------------------------
// SpMM: out[r,:] = sum_e vals[e] * H[cols[e],:].
// 4 rows per wave, one row per 16-lane group (4 consecutive rows -> contiguous
// CSR segments -> coalesced cols/vals loads). Up to 32 edges preloaded per
// group (covers 99.98% of Poisson(16) rows in one phase). Per-group j-loop
// bound: exec-mask skips finished groups (no wasted gathers). Each group holds
// all 128 channels of its row -> no reduction, direct coalesced store.
// ---------------------------------------------------------------------------
__global__ __launch_bounds__(256) void spmm_rows(const uint4* __restrict__ H4,
                                                 const int* __restrict__ rowptr,
                                                 const int* __restrict__ cols,
                                                 const float* __restrict__ vals,
                                                 float* __restrict__ out) {
    const int lane = threadIdx.x & 63;
    const int wid  = threadIdx.x >> 6;
    const int g    = lane >> 4;        // group 0..3 -> row within wave
    const int cg   = lane & 15;        // channel group: channels cg*8 .. +7
    const int glb  = g << 4;           // group lane base
    const int row  = (blockIdx.x * 4 + wid) * 4 + g;

    const int s = rowptr[row];
    const int e = rowptr[row + 1];

    float acc[8];
#pragma unroll
    for (int t = 0; t < 8; ++t) acc[t] = 0.f;

    for (int base = s; base < e; base += 32) {
        const int rem = e - base;
        const int cnt = rem < 32 ? rem : 32;
        int ec0 = 0, ec1 = 0;
        float ev0 = 0.f, ev1 = 0.f;
        if (cg < cnt)      { ec0 = cols[base + cg];      ev0 = vals[base + cg]; }
        if (cg + 16 < cnt) { ec1 = cols[base + 16 + cg]; ev1 = vals[base + 16 + cg]; }

        const int c1 = cnt < 16 ? cnt : 16;
#pragma unroll 4
        for (int j = 0; j < c1; ++j) {
            int   c = __shfl(ec0, glb + j);
            float v = __shfl(ev0, glb + j);
            uint4 u = H4[(size_t)c * 16 + cg];
            acc[0] += v * bflo(u.x); acc[1] += v * bfhi(u.x);
            acc[2] += v * bflo(u.y); acc[3] += v * bfhi(u.y);
            acc[4] += v * bflo(u.z); acc[5] += v * bfhi(u.z);
            acc[6] += v * bflo(u.w); acc[7] += v * bfhi(u.w);
        }
#pragma unroll 4
        for (int j = 16; j < cnt; ++j) {
            int   c = __shfl(ec1, glb + j - 16);
            float v = __shfl(ev1, glb + j - 16);
            uint4 u = H4[(size_t)c * 16 + cg];
            acc[0] += v * bflo(u.x); acc[1] += v * bfhi(u.x);
            acc[2] += v * bflo(u.y); acc[3] += v * bfhi(u.y);
            acc[4] += v * bflo(u.z); acc[5] += v * bfhi(u.z);
            acc[6] += v * bflo(u.w); acc[7] += v * bfhi(u.w);
        }
    }

    float4 v0 = make_float4(acc[0], acc[1], acc[2], acc[3]);
    float4 v1 = make_float4(acc[4], acc[5], acc[6], acc[7]);
    *(float4*)(out + (size_t)row * OUT_C + cg * 8)     = v0;
    *(float4*)(out + (size_t)row * OUT_C + cg * 8 + 4) = v1;
}

// ---------------------------------------------------------------------------
extern "C" void kernel_launch(void* const* d_in, const int* in_sizes, int n_in,
                              void* d_out, int out_size, void* d_ws, size_t ws_size,
                              hipStream_t stream) {
    const float* X      = (const float*)d_in[0];
    const float* W      = (const float*)d_in[1];
    const int*   A_rows = (const int*)d_in[2];
    const int*   A_cols = (const int*)d_in[3];
    const float* A_vals = (const float*)d_in[4];
    float* out = (float*)d_out;

    unsigned short* H   = (unsigned short*)d_ws;                    // 25.6 MB bf16
    int* rowptr = (int*)((char*)d_ws +
                         (size_t)NNODES * OUT_C * sizeof(unsigned short));

    gemm_xwt<<<(NNODES + 127) / 128, 512, 0, stream>>>(X, W, H);
    build_rowptr<<<(NNODES + 1 + 255) / 256, 256, 0, stream>>>(A_rows, rowptr);
    spmm_rows<<<NNODES / 16, 256, 0, stream>>>((const uint4*)H, rowptr,
                                               A_cols, A_vals, out);
}